// Round 7
// baseline (482.062 us; speedup 1.0000x reference)
//
#include <hip/hip_runtime.h>
#include <math.h>

#define NN   1536
#define DG   32
#define BB   8
#define OBSD 33
#define HID  64
#define NHEAD 4
#define EE   (NN*DG)   // 49152
#define MAXDEG 128     // actual max in-degree ~55 (multinomial mean 32, fixed seed)
#define EMB_BLOCKS (BB*NN/4)   // 3072
#define GRP_BLOCKS (EE/256)    // 192

__device__ __forceinline__ float sigm(float x){ return 1.0f/(1.0f+expf(-x)); }
// wave-uniform broadcast: readlane (VALU/SALU) instead of ds_bpermute (LDS pipe)
__device__ __forceinline__ float rl(float v, int l){
    return __int_as_float(__builtin_amdgcn_readlane(__float_as_int(v), l));
}

// ---------------- K0: ObsEmbedding + GRU input transform  (+ fused dst-grouping) -------
__global__ void __launch_bounds__(256) k_embgi(
                      const float* __restrict__ Ht,
                      const float* __restrict__ We1, const float* __restrict__ be1,
                      const float* __restrict__ We2, const float* __restrict__ be2,
                      const float* __restrict__ lng, const float* __restrict__ lnb,
                      const float* __restrict__ Wih, const float* __restrict__ bih,
                      float* __restrict__ GI,
                      const int* __restrict__ dst, int* __restrict__ cursor,
                      int* __restrict__ gedge){
    __shared__ float lwih[192*33];
    int tid = threadIdx.x;
    if(blockIdx.x >= EMB_BLOCKS){
        int e = (blockIdx.x - EMB_BLOCKS)*256 + tid;
        if(e<EE){
            int d = dst[e];
            int s = atomicAdd(&cursor[d],1);
            if(s<MAXDEG) gedge[d*MAXDEG+s]=e;
        }
        return;
    }
    for(int i=tid;i<192*32;i+=256){ int r=i>>5, c=i&31; lwih[r*33+c]=Wih[i]; }
    __syncthreads();
    int lane = tid & 63;
    int j32 = lane & 31;
    int bn = blockIdx.x*4 + (tid>>6);       // 0 .. B*N-1  (t-major)
    const float* hrow = Ht + (size_t)bn*OBSD;
    float x1 = be1[j32];
    for(int o=0;o<OBSD;o++) x1 += hrow[o]*We1[o*32+j32];
    x1 = fmaxf(x1,0.f);
    float x2 = be2[j32];
    for(int i=0;i<32;i++) x2 += rl(x1,i) * We2[i*32+j32];
    x2 = fmaxf(x2,0.f);
    float mu = x2;
    for(int m=16;m>=1;m>>=1) mu += __shfl_xor(mu, m, 32);
    mu *= (1.0f/32.0f);
    float d = x2-mu; float var = d*d;
    for(int m=16;m>=1;m>>=1) var += __shfl_xor(var, m, 32);
    var *= (1.0f/32.0f);
    float xln = d*rsqrtf(var+1e-5f)*lng[j32]+lnb[j32];
    int j = lane;
    float gr=bih[j], gz=bih[64+j], gn=bih[128+j];
    for(int kk=0;kk<32;kk++){
        float ek = rl(xln, kk);
        gr += ek*lwih[j*33+kk];
        gz += ek*lwih[(64+j)*33+kk];
        gn += ek*lwih[(128+j)*33+kk];
    }
    float* g = GI + (size_t)bn*192;
    g[j]=gr; g[64+j]=gz; g[128+j]=gn;
}

// ---------------- K1: ALL 8 GRU steps in one dispatch ----------------
__global__ void __launch_bounds__(384) k_gru_all(const float* __restrict__ GI,
                       const float* __restrict__ Whh, const float* __restrict__ bhh,
                       float* __restrict__ Hall){
    __shared__ float lw[192*65];
    int tid = threadIdx.x;
    for(int i=tid;i<192*64;i+=384){ int r=i>>6, c=i&63; lw[r*65+c]=Whh[i]; }
    __syncthreads();
    int node = blockIdx.x*6 + (tid>>6);
    int j = tid&63;
    float b_r=bhh[j], b_z=bhh[64+j], b_n=bhh[128+j];
    const float* lwr = lw + j*65;
    const float* lwz = lw + (64+j)*65;
    const float* lwn = lw + (128+j)*65;
    float hold = 0.f;                       // h0 = zeros
    for(int t=0;t<BB;t++){
        float hr=b_r, hz=b_z, hn=b_n;
        for(int kk=0;kk<64;kk++){
            float hk = rl(hold,kk);
            hr += hk*lwr[kk];
            hz += hk*lwz[kk];
            hn += hk*lwn[kk];
        }
        const float* g = GI + ((size_t)t*NN+node)*192;
        float r  = sigm(g[j]     + hr);
        float z  = sigm(g[64+j]  + hz);
        float nn_= tanhf(g[128+j] + r*hn);
        hold = (1.f-z)*nn_ + z*hold;
        Hall[((size_t)t*NN+node)*64 + j] = hold;
    }
}

// ---------------- K2: per-(t,n) P,Q (edge scorer halves) + xh + a_s,a_d ----------------
__global__ void __launch_bounds__(256) k_post(const float* __restrict__ Hall,
                       const float* __restrict__ Ws1, const float* __restrict__ Wgat,
                       const float* __restrict__ atts, const float* __restrict__ attd,
                       float* __restrict__ P, float* __restrict__ Q,
                       float* __restrict__ xh, float* __restrict__ as_, float* __restrict__ ad_){
    __shared__ float ws1l[128*64];
    __shared__ float wgl[64*32];
    int tid = threadIdx.x;
    for(int i=tid;i<128*64;i+=256) ws1l[i]=Ws1[i];
    for(int i=tid;i<64*32;i+=256)  wgl[i]=Wgat[i];
    __syncthreads();
    int bn = blockIdx.x*4 + (tid>>6);
    int j = tid&63;
    float hv = Hall[(size_t)bn*64+j];
    float p=0.f,q=0.f,xv=0.f;
    for(int kk=0;kk<64;kk++){
        float hk=rl(hv,kk);
        p += hk*ws1l[kk*64+j];
        q += hk*ws1l[(64+kk)*64+j];
        if(j<32) xv += hk*wgl[kk*32+j];
    }
    P[(size_t)bn*64+j]=p; Q[(size_t)bn*64+j]=q;
    if(j<32){
        xh[(size_t)bn*32+j]=xv;
        float asv = xv*atts[j];
        float adv = xv*attd[j];
        for(int m=1;m<8;m<<=1){ asv += __shfl_xor(asv,m); adv += __shfl_xor(adv,m); }
        if((j&7)==0){ as_[(size_t)bn*4+(j>>3)]=asv; ad_[(size_t)bn*4+(j>>3)]=adv; }
    }
}

// ---------------- K3: edge scores + top-k + per-edge exp, COALESCED ----------------
// Transposed parallelization: WAVE = one edge, lane = feature dim j. The Q-row read
// is one fully-coalesced 256 B load per edge (was: 16 per-lane 16 B gathers = 1024
// TA transactions per wave). Block = one (t,row): 4 waves x 8 sequential edges
// (8 independent Q loads preloaded per wave for MLP). Scores -> LDS, wave 0 runs
// top-k, then rec written 8 lanes/edge (coalesced 32 B stores).
__global__ void __launch_bounds__(256) k_edgescore(const float* __restrict__ P, const float* __restrict__ Q,
                       const float* __restrict__ bs1, const float* __restrict__ Ws2,
                       const float* __restrict__ bs2, const int* __restrict__ dst,
                       const int* __restrict__ kptr,
                       const float* __restrict__ as_, const float* __restrict__ ad_,
                       float* __restrict__ rec){
    __shared__ float sc[DG];
    __shared__ int   dsl[DG];
    __shared__ unsigned int keepm;
    int t = blockIdx.x;
    int row = blockIdx.y;
    int tid = threadIdx.x;
    int wv = tid>>6;          // wave 0..3
    int j  = tid&63;          // feature dim
    // per-wave uniform operands
    float pj  = P[((size_t)t*NN+row)*64 + j];
    float b1j = bs1[j];
    float w2j = Ws2[j];
    // preload 8 Q rows (coalesced 256B each, independent -> overlapped latency)
    const int ebase = row*DG + wv*8;
    int   de[8];
    float qv[8];
    #pragma unroll
    for(int i=0;i<8;i++){
        de[i] = dst[ebase+i];
        qv[i] = Q[((size_t)t*NN+de[i])*64 + j];
    }
    #pragma unroll
    for(int i=0;i<8;i++){
        float v = fmaxf(pj + qv[i] + b1j, 0.f) * w2j;
        #pragma unroll
        for(int m=32;m>=1;m>>=1) v += __shfl_xor(v, m);
        if(j==0){ sc[wv*8+i] = v; dsl[wv*8+i] = de[i]; }
    }
    __syncthreads();
    // wave 0, lanes 0..31: top-k over the 32 row scores
    if(tid < 32){
        float score = sigm(sc[tid] + bs2[0]);
        sc[tid] = score;                       // now holds sigmoid score
        int kk = kptr[0]; if(kk>32) kk=32; if(kk<0) kk=0;
        bool sel=false;
        for(int it=0; it<kk; it++){
            float v = sel ? -INFINITY : score;
            int idx = tid;
            for(int m=16;m>=1;m>>=1){
                float ov = __shfl_xor(v,m,32);
                int   oi = __shfl_xor(idx,m,32);
                if(ov>v || (ov==v && oi<idx)){ v=ov; idx=oi; }  // tie-break: lowest index
            }
            if(idx==tid) sel=true;
        }
        unsigned int ballot = (unsigned int)(__ballot(sel) & 0xffffffffull);
        if(tid==0) keepm = ballot;
    }
    __syncthreads();
    // rec write: 8 lanes per edge (32B record), 256 lanes = 32 edges, fully coalesced.
    // lane tid: edge d = tid>>3, field f = tid&7.
    int d = tid>>3, f = tid&7;
    int e = row*DG + d;
    float wval = ((keepm>>d)&1u) ? sc[d] : 0.f;
    float out;
    if(f < 4){
        int dei = dsl[(d&~7)] ; // placeholder overwritten below
        dei = dsl[d];
        float asv = as_[((size_t)t*NN+row)*4 + f];
        float adv = ad_[((size_t)t*NN+dei)*4 + f];
        float l = asv + adv; l = l>0.f ? l : 0.2f*l;
        out = (wval>0.f) ? expf(l) : 0.f;
    } else if(f == 4){
        out = wval;
    } else {
        out = 0.f;
    }
    rec[((size_t)t*EE + e)*8 + f] = out;
}

// ---------------- K4: per-dst softmax-sum + message aggregation ----------------
__global__ void __launch_bounds__(256) k_soft2(const int* __restrict__ gcnt, const int* __restrict__ gedge,
                       const float* __restrict__ rec, const float* __restrict__ xhb,
                       const float* __restrict__ bgat,
                       float* __restrict__ ssum, float* __restrict__ outp){
    int t = blockIdx.x;
    int n = blockIdx.y*4 + (threadIdx.x>>6);
    int lane = threadIdx.x & 63;
    const float* rt   = rec + (size_t)t*EE*8;
    const float* xhbt = xhb + (size_t)t*NN*32;
    int cnt = gcnt[n]; if(cnt>MAXDEG) cnt=MAXDEG;
    const int* ge = gedge + (size_t)n*MAXDEG;

    int   e0=0, e1=0;
    float w0=0.f, w1=0.f;
    float4 x0v = make_float4(0,0,0,0), x1v = make_float4(0,0,0,0);
    bool h0v = lane < cnt, h1v = 64+lane < cnt;
    if(h0v){
        e0 = ge[lane];
        const float4* r = (const float4*)(rt + (size_t)e0*8);
        x0v = r[0]; w0 = r[1].x;
    }
    if(h1v){
        e1 = ge[64+lane];
        const float4* r = (const float4*)(rt + (size_t)e1*8);
        x1v = r[0]; w1 = r[1].x;
    }
    float ss[4] = { x0v.x+x1v.x, x0v.y+x1v.y, x0v.z+x1v.z, x0v.w+x1v.w };
    #pragma unroll
    for(int mm=32;mm>=1;mm>>=1){
        #pragma unroll
        for(int h=0;h<4;h++) ss[h] += __shfl_xor(ss[h], mm);
    }
    float inv[4];
    #pragma unroll
    for(int h=0;h<4;h++) inv[h] = 1.0f/fmaxf(ss[h],1e-16f);

    float acc[32];
    #pragma unroll
    for(int c=0;c<32;c++) acc[c]=0.f;

    if(h0v && w0>0.f){
        const float4* xr4 = (const float4*)(xhbt + (size_t)(e0>>5)*32);
        float a0[4] = { x0v.x*inv[0], x0v.y*inv[1], x0v.z*inv[2], x0v.w*inv[3] };
        #pragma unroll
        for(int h=0;h<4;h++){
            float aw = a0[h]*w0;
            float4 xa = xr4[h*2], xb = xr4[h*2+1];
            acc[h*8+0]+=aw*xa.x; acc[h*8+1]+=aw*xa.y; acc[h*8+2]+=aw*xa.z; acc[h*8+3]+=aw*xa.w;
            acc[h*8+4]+=aw*xb.x; acc[h*8+5]+=aw*xb.y; acc[h*8+6]+=aw*xb.z; acc[h*8+7]+=aw*xb.w;
        }
    }
    if(h1v && w1>0.f){
        const float4* xr4 = (const float4*)(xhbt + (size_t)(e1>>5)*32);
        float a1[4] = { x1v.x*inv[0], x1v.y*inv[1], x1v.z*inv[2], x1v.w*inv[3] };
        #pragma unroll
        for(int h=0;h<4;h++){
            float aw = a1[h]*w1;
            float4 xa = xr4[h*2], xb = xr4[h*2+1];
            acc[h*8+0]+=aw*xa.x; acc[h*8+1]+=aw*xa.y; acc[h*8+2]+=aw*xa.z; acc[h*8+3]+=aw*xa.w;
            acc[h*8+4]+=aw*xb.x; acc[h*8+5]+=aw*xb.y; acc[h*8+6]+=aw*xb.z; acc[h*8+7]+=aw*xb.w;
        }
    }
    #pragma unroll
    for(int mm=32;mm>=1;mm>>=1){
        #pragma unroll
        for(int c=0;c<32;c++) acc[c] += __shfl_xor(acc[c], mm);
    }
    if(lane==0){
        *(float4*)(ssum + ((size_t)t*NN+n)*4) = make_float4(ss[0],ss[1],ss[2],ss[3]);
        float4* o = (float4*)(outp + ((size_t)t*NN+n)*32);
        const float4* bg4 = (const float4*)bgat;
        #pragma unroll
        for(int q8=0;q8<8;q8++){
            float4 b = bg4[q8];
            o[q8] = make_float4(acc[q8*4]+b.x, acc[q8*4+1]+b.y, acc[q8*4+2]+b.z, acc[q8*4+3]+b.w);
        }
    }
}

// ---------------- K5: dense A row build straight from rec + ssum ----------------
__global__ void __launch_bounds__(256) k_scatter(const float* __restrict__ rec,
                       const float* __restrict__ ssum,
                       const int* __restrict__ dst, float* __restrict__ attn){
    __shared__ float rowbuf[NHEAD][NN];
    __shared__ float rs[NHEAD];
    __shared__ float rsf[NHEAD];
    int t = blockIdx.x;
    int n = blockIdx.y;
    int tid = threadIdx.x;
    for(int i=tid;i<NHEAD*(NN/4);i+=256) ((float4*)rowbuf)[i]=make_float4(0.f,0.f,0.f,0.f);
    if(tid<NHEAD) rs[tid]=0.f;
    __syncthreads();
    float a=0.f; int de=0; int h=0;
    if(tid<128){
        int d = tid>>2; h = tid&3;
        int e = n*DG+d;
        float ex = rec[((size_t)t*EE + e)*8 + h];
        de = dst[e];
        if(ex>0.f){
            float ssv = ssum[((size_t)t*NN+de)*4 + h];
            a = ex / fmaxf(ssv, 1e-16f);
            atomicAdd(&rs[h], a);
        }
    }
    __syncthreads();
    if(tid<NHEAD) rsf[tid] = 1.0f/fmaxf(rs[tid],1e-9f);
    __syncthreads();
    if(tid<128 && a>0.f) atomicAdd(&rowbuf[h][de], a*rsf[h]);
    __syncthreads();
    size_t tb = (size_t)t*NHEAD*NN*NN;
    for(int i=tid;i<NHEAD*(NN/4);i+=256){
        int hh = i/(NN/4); int c4 = i%(NN/4);
        float4 v = ((const float4*)rowbuf[hh])[c4];
        ((float4*)(attn + tb + (size_t)hh*NN*NN + (size_t)n*NN))[c4] = v;
    }
}

extern "C" void kernel_launch(void* const* d_in, const int* in_sizes, int n_in,
                              void* d_out, int out_size, void* d_ws, size_t ws_size,
                              hipStream_t stream) {
    const float* Ht   = (const float*)d_in[0];
    const int*   src  = (const int*)  d_in[1];
    const int*   dst  = (const int*)  d_in[2];
    const int*   kptr = (const int*)  d_in[3];
    const float* We1  = (const float*)d_in[4];
    const float* be1  = (const float*)d_in[5];
    const float* We2  = (const float*)d_in[6];
    const float* be2  = (const float*)d_in[7];
    const float* lng  = (const float*)d_in[8];
    const float* lnb  = (const float*)d_in[9];
    const float* Wih  = (const float*)d_in[10];
    const float* Whh  = (const float*)d_in[11];
    const float* bih  = (const float*)d_in[12];
    const float* bhh  = (const float*)d_in[13];
    const float* Ws1  = (const float*)d_in[14];
    const float* bs1  = (const float*)d_in[15];
    const float* Ws2  = (const float*)d_in[16];
    const float* bs2  = (const float*)d_in[17];
    const float* Wgat = (const float*)d_in[18];
    const float* atts = (const float*)d_in[19];
    const float* attd = (const float*)d_in[20];
    const float* bgat = (const float*)d_in[21];
    (void)src;

    float* outp = (float*)d_out;                       // (B,N,32)
    float* attn = outp + (size_t)BB*NN*32;             // (B,HEADS,N,N)

    // workspace layout (floats)
    float* ws    = (float*)d_ws;
    float* GI    = ws;                    // 2359296
    float* Hall  = ws + 2359296;          //  786432
    float* P     = ws + 3145728;          //  786432
    float* Q     = ws + 3932160;          //  786432
    float* xh    = ws + 4718592;          //  393216
    float* as_   = ws + 5111808;          //   49152
    float* ad_   = ws + 5160960;          //   49152
    float* ssum  = ws + 5210112;          //   49152
    float* rec   = ws + 5259264;          // EE*8*BB = 3145728
    int*   ibase = (int*)(ws + 8404992);
    int*   cursor= ibase;                 // NN (pad to 2048)
    int*   gedge = ibase + 2048;          // NN*MAXDEG

    hipMemsetAsync(cursor, 0, (size_t)NN*sizeof(int), stream);

    k_embgi<<<EMB_BLOCKS+GRP_BLOCKS, 256, 0, stream>>>(Ht, We1, be1, We2, be2, lng, lnb,
                                                       Wih, bih, GI, dst, cursor, gedge);
    k_gru_all<<<NN/6, 384, 0, stream>>>(GI, Whh, bhh, Hall);
    k_post<<<BB*NN/4, 256, 0, stream>>>(Hall, Ws1, Wgat, atts, attd, P, Q, xh, as_, ad_);
    {
        dim3 g(BB, NN);          // block = one (t, src row)
        k_edgescore<<<g, 256, 0, stream>>>(P, Q, bs1, Ws2, bs2, dst, kptr, as_, ad_, rec);
    }
    {
        dim3 gs(BB, NN/4);
        k_soft2<<<gs, 256, 0, stream>>>(cursor, gedge, rec, xh, bgat, ssum, outp);
        dim3 g(BB, NN);
        k_scatter<<<g, 256, 0, stream>>>(rec, ssum, dst, attn);
    }
}

// Round 9
// 471.600 us; speedup vs baseline: 1.0222x; 1.0222x over previous
//
#include <hip/hip_runtime.h>
#include <math.h>

#define NN   1536
#define DG   32
#define BB   8
#define OBSD 33
#define HID  64
#define NHEAD 4
#define EE   (NN*DG)   // 49152
#define MAXDEG 128     // actual max in-degree ~55 (multinomial mean 32, fixed seed)
#define EMB_BLOCKS (BB*NN/4)   // 3072
#define GRP_BLOCKS (EE/256)    // 192

typedef float nf4 __attribute__((ext_vector_type(4)));   // native vec4 for nontemporal builtins

__device__ __forceinline__ float sigm(float x){ return 1.0f/(1.0f+expf(-x)); }
// wave-uniform broadcast: readlane (VALU/SALU) instead of ds_bpermute (LDS pipe)
__device__ __forceinline__ float rl(float v, int l){
    return __int_as_float(__builtin_amdgcn_readlane(__float_as_int(v), l));
}

// ---------------- K0: ObsEmbedding + GRU input transform  (+ fused dst-grouping) -------
__global__ void __launch_bounds__(256) k_embgi(
                      const float* __restrict__ Ht,
                      const float* __restrict__ We1, const float* __restrict__ be1,
                      const float* __restrict__ We2, const float* __restrict__ be2,
                      const float* __restrict__ lng, const float* __restrict__ lnb,
                      const float* __restrict__ Wih, const float* __restrict__ bih,
                      float* __restrict__ GI,
                      const int* __restrict__ dst, int* __restrict__ cursor,
                      int* __restrict__ gedge){
    __shared__ float lwih[192*33];
    int tid = threadIdx.x;
    if(blockIdx.x >= EMB_BLOCKS){
        int e = (blockIdx.x - EMB_BLOCKS)*256 + tid;
        if(e<EE){
            int d = dst[e];
            int s = atomicAdd(&cursor[d],1);
            if(s<MAXDEG) gedge[d*MAXDEG+s]=e;
        }
        return;
    }
    for(int i=tid;i<192*32;i+=256){ int r=i>>5, c=i&31; lwih[r*33+c]=Wih[i]; }
    __syncthreads();
    int lane = tid & 63;
    int j32 = lane & 31;
    int bn = blockIdx.x*4 + (tid>>6);       // 0 .. B*N-1  (t-major)
    const float* hrow = Ht + (size_t)bn*OBSD;
    float x1 = be1[j32];
    for(int o=0;o<OBSD;o++) x1 += hrow[o]*We1[o*32+j32];
    x1 = fmaxf(x1,0.f);
    float x2 = be2[j32];
    for(int i=0;i<32;i++) x2 += rl(x1,i) * We2[i*32+j32];
    x2 = fmaxf(x2,0.f);
    float mu = x2;
    for(int m=16;m>=1;m>>=1) mu += __shfl_xor(mu, m, 32);
    mu *= (1.0f/32.0f);
    float d = x2-mu; float var = d*d;
    for(int m=16;m>=1;m>>=1) var += __shfl_xor(var, m, 32);
    var *= (1.0f/32.0f);
    float xln = d*rsqrtf(var+1e-5f)*lng[j32]+lnb[j32];
    int j = lane;
    float gr=bih[j], gz=bih[64+j], gn=bih[128+j];
    for(int kk=0;kk<32;kk++){
        float ek = rl(xln, kk);
        gr += ek*lwih[j*33+kk];
        gz += ek*lwih[(64+j)*33+kk];
        gn += ek*lwih[(128+j)*33+kk];
    }
    float* g = GI + (size_t)bn*192;
    g[j]=gr; g[64+j]=gz; g[128+j]=gn;
}

// ---------------- K1: ALL 8 GRU steps in one dispatch ----------------
__global__ void __launch_bounds__(384) k_gru_all(const float* __restrict__ GI,
                       const float* __restrict__ Whh, const float* __restrict__ bhh,
                       float* __restrict__ Hall){
    __shared__ float lw[192*65];
    int tid = threadIdx.x;
    for(int i=tid;i<192*64;i+=384){ int r=i>>6, c=i&63; lw[r*65+c]=Whh[i]; }
    __syncthreads();
    int node = blockIdx.x*6 + (tid>>6);
    int j = tid&63;
    float b_r=bhh[j], b_z=bhh[64+j], b_n=bhh[128+j];
    const float* lwr = lw + j*65;
    const float* lwz = lw + (64+j)*65;
    const float* lwn = lw + (128+j)*65;
    float hold = 0.f;                       // h0 = zeros
    for(int t=0;t<BB;t++){
        float hr=b_r, hz=b_z, hn=b_n;
        for(int kk=0;kk<64;kk++){
            float hk = rl(hold,kk);
            hr += hk*lwr[kk];
            hz += hk*lwz[kk];
            hn += hk*lwn[kk];
        }
        const float* g = GI + ((size_t)t*NN+node)*192;
        float r  = sigm(g[j]     + hr);
        float z  = sigm(g[64+j]  + hz);
        float nn_= tanhf(g[128+j] + r*hn);
        hold = (1.f-z)*nn_ + z*hold;
        Hall[((size_t)t*NN+node)*64 + j] = hold;
    }
}

// ---------------- K2: per-(t,n) P,Q (edge scorer halves) + xh + a_s,a_d ----------------
__global__ void __launch_bounds__(256) k_post(const float* __restrict__ Hall,
                       const float* __restrict__ Ws1, const float* __restrict__ Wgat,
                       const float* __restrict__ atts, const float* __restrict__ attd,
                       float* __restrict__ P, float* __restrict__ Q,
                       float* __restrict__ xh, float* __restrict__ as_, float* __restrict__ ad_){
    __shared__ float ws1l[128*64];
    __shared__ float wgl[64*32];
    int tid = threadIdx.x;
    for(int i=tid;i<128*64;i+=256) ws1l[i]=Ws1[i];
    for(int i=tid;i<64*32;i+=256)  wgl[i]=Wgat[i];
    __syncthreads();
    int bn = blockIdx.x*4 + (tid>>6);
    int j = tid&63;
    float hv = Hall[(size_t)bn*64+j];
    float p=0.f,q=0.f,xv=0.f;
    for(int kk=0;kk<64;kk++){
        float hk=rl(hv,kk);
        p += hk*ws1l[kk*64+j];
        q += hk*ws1l[(64+kk)*64+j];
        if(j<32) xv += hk*wgl[kk*32+j];
    }
    P[(size_t)bn*64+j]=p; Q[(size_t)bn*64+j]=q;
    if(j<32){
        xh[(size_t)bn*32+j]=xv;
        float asv = xv*atts[j];
        float adv = xv*attd[j];
        for(int m=1;m<8;m<<=1){ asv += __shfl_xor(asv,m); adv += __shfl_xor(adv,m); }
        if((j&7)==0){ as_[(size_t)bn*4+(j>>3)]=asv; ad_[(size_t)bn*4+(j>>3)]=adv; }
    }
}

// ---------------- K3: edge scores + top-k + per-edge exp, src-grouped ----------------
// (R5/R6 proven version.) Writes packed rec[e] = {ex0..ex3, w,_,_,_} (32B, coalesced).
__global__ void __launch_bounds__(256) k_edgescore(const float* __restrict__ P, const float* __restrict__ Q,
                       const float* __restrict__ bs1, const float* __restrict__ Ws2,
                       const float* __restrict__ bs2, const int* __restrict__ dst,
                       const int* __restrict__ kptr,
                       const float* __restrict__ as_, const float* __restrict__ ad_,
                       float* __restrict__ rec){
    int t = blockIdx.x;
    int row = blockIdx.y*8 + (threadIdx.x>>5);
    int d = threadIdx.x & 31;
    int e = row*DG + d;
    int de = dst[e];
    const float4* Pr = (const float4*)(P + ((size_t)t*NN+row)*64);
    const float4* Qr = (const float4*)(Q + ((size_t)t*NN+de)*64);
    const float4* B1 = (const float4*)bs1;
    const float4* W2 = (const float4*)Ws2;
    float acc = 0.f;
    #pragma unroll
    for(int jj=0;jj<16;jj++){
        float4 pv=Pr[jj], qv=Qr[jj], bv=B1[jj], wv=W2[jj];
        acc += fmaxf(pv.x+qv.x+bv.x,0.f)*wv.x;
        acc += fmaxf(pv.y+qv.y+bv.y,0.f)*wv.y;
        acc += fmaxf(pv.z+qv.z+bv.z,0.f)*wv.z;
        acc += fmaxf(pv.w+qv.w+bv.w,0.f)*wv.w;
    }
    float score = sigm(acc + bs2[0]);
    int kk = kptr[0]; if(kk>32) kk=32; if(kk<0) kk=0;
    bool sel=false;
    for(int it=0; it<kk; it++){
        float v = sel ? -INFINITY : score;
        int idx = d;
        for(int m=16;m>=1;m>>=1){
            float ov = __shfl_xor(v,m,32);
            int   oi = __shfl_xor(idx,m,32);
            if(ov>v || (ov==v && oi<idx)){ v=ov; idx=oi; }  // top_k tie-break: lowest index
        }
        if(idx==d) sel=true;
    }
    float wv = sel ? score : 0.f;
    float4 asq = *(const float4*)(as_ + ((size_t)t*NN+row)*4);  // row-uniform broadcast
    float4 adq = *(const float4*)(ad_ + ((size_t)t*NN+de)*4);   // one 16B gather
    float ex0,ex1,ex2,ex3;
    {
        float l;
        l = asq.x+adq.x; l = l>0.f ? l : 0.2f*l; ex0 = (wv>0.f)?expf(l):0.f;
        l = asq.y+adq.y; l = l>0.f ? l : 0.2f*l; ex1 = (wv>0.f)?expf(l):0.f;
        l = asq.z+adq.z; l = l>0.f ? l : 0.2f*l; ex2 = (wv>0.f)?expf(l):0.f;
        l = asq.w+adq.w; l = l>0.f ? l : 0.2f*l; ex3 = (wv>0.f)?expf(l):0.f;
    }
    float4* r = (float4*)(rec + ((size_t)t*EE + e)*8);
    r[0] = make_float4(ex0,ex1,ex2,ex3);
    r[1] = make_float4(wv, 0.f, 0.f, 0.f);
}

// ---------------- K4: per-dst softmax-sum + message aggregation ----------------
__global__ void __launch_bounds__(256) k_soft2(const int* __restrict__ gcnt, const int* __restrict__ gedge,
                       const float* __restrict__ rec, const float* __restrict__ xhb,
                       const float* __restrict__ bgat,
                       float* __restrict__ ssum, float* __restrict__ outp){
    int t = blockIdx.x;
    int n = blockIdx.y*4 + (threadIdx.x>>6);
    int lane = threadIdx.x & 63;
    const float* rt   = rec + (size_t)t*EE*8;
    const float* xhbt = xhb + (size_t)t*NN*32;
    int cnt = gcnt[n]; if(cnt>MAXDEG) cnt=MAXDEG;
    const int* ge = gedge + (size_t)n*MAXDEG;

    int   e0=0, e1=0;
    float w0=0.f, w1=0.f;
    float4 x0v = make_float4(0,0,0,0), x1v = make_float4(0,0,0,0);
    bool h0v = lane < cnt, h1v = 64+lane < cnt;
    if(h0v){
        e0 = ge[lane];
        const float4* r = (const float4*)(rt + (size_t)e0*8);
        x0v = r[0]; w0 = r[1].x;
    }
    if(h1v){
        e1 = ge[64+lane];
        const float4* r = (const float4*)(rt + (size_t)e1*8);
        x1v = r[0]; w1 = r[1].x;
    }
    float ss[4] = { x0v.x+x1v.x, x0v.y+x1v.y, x0v.z+x1v.z, x0v.w+x1v.w };
    #pragma unroll
    for(int mm=32;mm>=1;mm>>=1){
        #pragma unroll
        for(int h=0;h<4;h++) ss[h] += __shfl_xor(ss[h], mm);
    }
    float inv[4];
    #pragma unroll
    for(int h=0;h<4;h++) inv[h] = 1.0f/fmaxf(ss[h],1e-16f);

    float acc[32];
    #pragma unroll
    for(int c=0;c<32;c++) acc[c]=0.f;

    if(h0v && w0>0.f){
        const float4* xr4 = (const float4*)(xhbt + (size_t)(e0>>5)*32);
        float a0[4] = { x0v.x*inv[0], x0v.y*inv[1], x0v.z*inv[2], x0v.w*inv[3] };
        #pragma unroll
        for(int h=0;h<4;h++){
            float aw = a0[h]*w0;
            float4 xa = xr4[h*2], xb = xr4[h*2+1];
            acc[h*8+0]+=aw*xa.x; acc[h*8+1]+=aw*xa.y; acc[h*8+2]+=aw*xa.z; acc[h*8+3]+=aw*xa.w;
            acc[h*8+4]+=aw*xb.x; acc[h*8+5]+=aw*xb.y; acc[h*8+6]+=aw*xb.z; acc[h*8+7]+=aw*xb.w;
        }
    }
    if(h1v && w1>0.f){
        const float4* xr4 = (const float4*)(xhbt + (size_t)(e1>>5)*32);
        float a1[4] = { x1v.x*inv[0], x1v.y*inv[1], x1v.z*inv[2], x1v.w*inv[3] };
        #pragma unroll
        for(int h=0;h<4;h++){
            float aw = a1[h]*w1;
            float4 xa = xr4[h*2], xb = xr4[h*2+1];
            acc[h*8+0]+=aw*xa.x; acc[h*8+1]+=aw*xa.y; acc[h*8+2]+=aw*xa.z; acc[h*8+3]+=aw*xa.w;
            acc[h*8+4]+=aw*xb.x; acc[h*8+5]+=aw*xb.y; acc[h*8+6]+=aw*xb.z; acc[h*8+7]+=aw*xb.w;
        }
    }
    #pragma unroll
    for(int mm=32;mm>=1;mm>>=1){
        #pragma unroll
        for(int c=0;c<32;c++) acc[c] += __shfl_xor(acc[c], mm);
    }
    if(lane==0){
        *(float4*)(ssum + ((size_t)t*NN+n)*4) = make_float4(ss[0],ss[1],ss[2],ss[3]);
        float4* o = (float4*)(outp + ((size_t)t*NN+n)*32);
        const float4* bg4 = (const float4*)bgat;
        #pragma unroll
        for(int q8=0;q8<8;q8++){
            float4 b = bg4[q8];
            o[q8] = make_float4(acc[q8*4]+b.x, acc[q8*4+1]+b.y, acc[q8*4+2]+b.z, acc[q8*4+3]+b.w);
        }
    }
}

// ---------------- K5: dense A row build straight from rec + ssum ----------------
// Streaming write uses nontemporal stores via native ext_vector_type (302 MB,
// write-once, nothing downstream re-reads it -> skip L2 write-allocate churn).
__global__ void __launch_bounds__(256) k_scatter(const float* __restrict__ rec,
                       const float* __restrict__ ssum,
                       const int* __restrict__ dst, float* __restrict__ attn){
    __shared__ float rowbuf[NHEAD][NN];
    __shared__ float rs[NHEAD];
    __shared__ float rsf[NHEAD];
    int t = blockIdx.x;
    int n = blockIdx.y;
    int tid = threadIdx.x;
    for(int i=tid;i<NHEAD*(NN/4);i+=256) ((float4*)rowbuf)[i]=make_float4(0.f,0.f,0.f,0.f);
    if(tid<NHEAD) rs[tid]=0.f;
    __syncthreads();
    float a=0.f; int de=0; int h=0;
    if(tid<128){
        int d = tid>>2; h = tid&3;
        int e = n*DG+d;
        float ex = rec[((size_t)t*EE + e)*8 + h];
        de = dst[e];
        if(ex>0.f){
            float ssv = ssum[((size_t)t*NN+de)*4 + h];
            a = ex / fmaxf(ssv, 1e-16f);
            atomicAdd(&rs[h], a);
        }
    }
    __syncthreads();
    if(tid<NHEAD) rsf[tid] = 1.0f/fmaxf(rs[tid],1e-9f);
    __syncthreads();
    if(tid<128 && a>0.f) atomicAdd(&rowbuf[h][de], a*rsf[h]);
    __syncthreads();
    size_t tb = (size_t)t*NHEAD*NN*NN;
    for(int i=tid;i<NHEAD*(NN/4);i+=256){
        int hh = i/(NN/4); int c4 = i%(NN/4);
        nf4 v = ((const nf4*)rowbuf[hh])[c4];
        nf4* dp = ((nf4*)(attn + tb + (size_t)hh*NN*NN + (size_t)n*NN)) + c4;
        __builtin_nontemporal_store(v, dp);
    }
}

extern "C" void kernel_launch(void* const* d_in, const int* in_sizes, int n_in,
                              void* d_out, int out_size, void* d_ws, size_t ws_size,
                              hipStream_t stream) {
    const float* Ht   = (const float*)d_in[0];
    const int*   src  = (const int*)  d_in[1];
    const int*   dst  = (const int*)  d_in[2];
    const int*   kptr = (const int*)  d_in[3];
    const float* We1  = (const float*)d_in[4];
    const float* be1  = (const float*)d_in[5];
    const float* We2  = (const float*)d_in[6];
    const float* be2  = (const float*)d_in[7];
    const float* lng  = (const float*)d_in[8];
    const float* lnb  = (const float*)d_in[9];
    const float* Wih  = (const float*)d_in[10];
    const float* Whh  = (const float*)d_in[11];
    const float* bih  = (const float*)d_in[12];
    const float* bhh  = (const float*)d_in[13];
    const float* Ws1  = (const float*)d_in[14];
    const float* bs1  = (const float*)d_in[15];
    const float* Ws2  = (const float*)d_in[16];
    const float* bs2  = (const float*)d_in[17];
    const float* Wgat = (const float*)d_in[18];
    const float* atts = (const float*)d_in[19];
    const float* attd = (const float*)d_in[20];
    const float* bgat = (const float*)d_in[21];
    (void)src;

    float* outp = (float*)d_out;                       // (B,N,32)
    float* attn = outp + (size_t)BB*NN*32;             // (B,HEADS,N,N)

    // workspace layout (floats)
    float* ws    = (float*)d_ws;
    float* GI    = ws;                    // 2359296
    float* Hall  = ws + 2359296;          //  786432
    float* P     = ws + 3145728;          //  786432
    float* Q     = ws + 3932160;          //  786432
    float* xh    = ws + 4718592;          //  393216
    float* as_   = ws + 5111808;          //   49152
    float* ad_   = ws + 5160960;          //   49152
    float* ssum  = ws + 5210112;          //   49152
    float* rec   = ws + 5259264;          // EE*8*BB = 3145728
    int*   ibase = (int*)(ws + 8404992);
    int*   cursor= ibase;                 // NN (pad to 2048)
    int*   gedge = ibase + 2048;          // NN*MAXDEG

    (void)hipMemsetAsync(cursor, 0, (size_t)NN*sizeof(int), stream);

    k_embgi<<<EMB_BLOCKS+GRP_BLOCKS, 256, 0, stream>>>(Ht, We1, be1, We2, be2, lng, lnb,
                                                       Wih, bih, GI, dst, cursor, gedge);
    k_gru_all<<<NN/6, 384, 0, stream>>>(GI, Whh, bhh, Hall);
    k_post<<<BB*NN/4, 256, 0, stream>>>(Hall, Ws1, Wgat, atts, attd, P, Q, xh, as_, ad_);
    {
        dim3 g(BB, NN/8);
        k_edgescore<<<g, 256, 0, stream>>>(P, Q, bs1, Ws2, bs2, dst, kptr, as_, ad_, rec);
    }
    {
        dim3 gs(BB, NN/4);
        k_soft2<<<gs, 256, 0, stream>>>(cursor, gedge, rec, xh, bgat, ssum, outp);
        dim3 g(BB, NN);
        k_scatter<<<g, 256, 0, stream>>>(rec, ssum, dst, attn);
    }
}